// Round 2
// baseline (37158.121 us; speedup 1.0000x reference)
//
#include <hip/hip_runtime.h>
#include <hip/hip_bf16.h>

// VQ-VAE forward. All d_in / d_out tensors are fp32 (per reference). fp32 accumulate.
// Spatial fixed 128x128, batch 16.

#define HWDIM 128
#define HWSQ  16384   // 128*128

__device__ __forceinline__ float ldv(const float* p) { return *p; }
__device__ __forceinline__ float ldv(const __hip_bfloat16* p) { return __bfloat162float(*p); }
__device__ __forceinline__ void stv(float* p, float v) { *p = v; }
__device__ __forceinline__ void stv(__hip_bfloat16* p, float v) { *p = __float2bfloat16(v); }

// ACT: 0 = relu, 1 = sigmoid
// TRANS: weight is (Cin, Cout, 3, 3) with spatial flip (ConvTranspose2d s=1 p=1 equivalence)
template <typename Tin, typename Tw, typename Tout, int ACT, bool TRANS>
__launch_bounds__(256)
__global__ void conv3x3_k(const Tin* __restrict__ in,
                          const Tw* __restrict__ wgt,
                          const Tw* __restrict__ bias,
                          Tout* __restrict__ out,
                          int Bn, int Cin, int Cout)
{
    int idx = blockIdx.x * 256 + threadIdx.x;
    int total = Bn * Cout * HWSQ;
    if (idx >= total) return;

    int w  = idx & (HWDIM - 1);
    int h  = (idx >> 7) & (HWDIM - 1);
    int t  = idx >> 14;           // b*Cout + oc
    int oc = t % Cout;
    int b  = t / Cout;

    float acc = ldv(bias + oc);
    const Tin* inb = in + (size_t)b * Cin * HWSQ;

    #pragma unroll
    for (int kh = 0; kh < 3; ++kh) {
        int ih = h + kh - 1;
        if ((unsigned)ih >= HWDIM) continue;
        #pragma unroll
        for (int kw = 0; kw < 3; ++kw) {
            int iw = w + kw - 1;
            if ((unsigned)iw >= HWDIM) continue;
            const Tin* ip = inb + ih * HWDIM + iw;
            const Tw* wp;
            int wstride;
            if (TRANS) {
                // w_eff[oc][ic][kh][kw] = w[ic][oc][2-kh][2-kw], w shape (Cin,Cout,3,3)
                wp = wgt + oc * 9 + (2 - kh) * 3 + (2 - kw);
                wstride = Cout * 9;
            } else {
                // OIHW
                wp = wgt + (size_t)oc * Cin * 9 + kh * 3 + kw;
                wstride = 9;
            }
            for (int ic = 0; ic < Cin; ++ic) {
                acc += ldv(ip + (size_t)ic * HWSQ) * ldv(wp + ic * wstride);
            }
        }
    }

    if (ACT == 0) acc = fmaxf(acc, 0.0f);
    else          acc = 1.0f / (1.0f + __expf(-acc));
    stv(out + idx, acc);
}

// Vector quantizer: rows are 8 consecutive elements of flattened NCHW z.
// argmin over 512 codes of (||e||^2 - 2 z.e)  (||z||^2 is row-constant).
template <typename T>
__launch_bounds__(256)
__global__ void vq_k(const T* __restrict__ z, const float* __restrict__ emb,
                     T* __restrict__ q, float* __restrict__ loss_acc, int nrows)
{
    __shared__ float se[512 * 8];
    __shared__ float se2[512];
    __shared__ float red[4];

    for (int i = threadIdx.x; i < 512 * 8; i += 256) se[i] = emb[i];
    __syncthreads();
    for (int k = threadIdx.x; k < 512; k += 256) {
        float s = 0.0f;
        #pragma unroll
        for (int j = 0; j < 8; ++j) { float e = se[k * 8 + j]; s += e * e; }
        se2[k] = s;
    }
    __syncthreads();

    int r = blockIdx.x * 256 + threadIdx.x;
    float lsum = 0.0f;
    if (r < nrows) {
        float zv[8];
        #pragma unroll
        for (int j = 0; j < 8; ++j) zv[j] = ldv(z + (size_t)r * 8 + j);

        float best = 3.4e38f;
        int bi = 0;
        for (int k = 0; k < 512; ++k) {
            float dot = 0.0f;
            #pragma unroll
            for (int j = 0; j < 8; ++j) dot += se[k * 8 + j] * zv[j];
            float d = se2[k] - 2.0f * dot;
            if (d < best) { best = d; bi = k; }   // strict < keeps first min (argmin semantics)
        }
        #pragma unroll
        for (int j = 0; j < 8; ++j) {
            float e = se[bi * 8 + j];
            stv(q + (size_t)r * 8 + j, e);
            float df = e - zv[j];
            lsum += df * df;
        }
    }

    // wave + block reduction
    for (int o = 32; o > 0; o >>= 1) lsum += __shfl_down(lsum, o, 64);
    int lane = threadIdx.x & 63, wv = threadIdx.x >> 6;
    if (lane == 0) red[wv] = lsum;
    __syncthreads();
    if (threadIdx.x == 0) atomicAdd(loss_acc, red[0] + red[1] + red[2] + red[3]);
}

__global__ void zero_k(float* p) { *p = 0.0f; }

__global__ void fin_k(const float* __restrict__ loss, float* __restrict__ out)
{
    // vq_loss = (1 + 0.25) * mean((q - z)^2), mean over 16*8*128*128 = 2097152 elems
    out[0] = 1.25f * (*loss) / 2097152.0f;
}

static inline int nblk(long long n) { return (int)((n + 255) / 256); }

extern "C" void kernel_launch(void* const* d_in, const int* in_sizes, int n_in,
                              void* d_out, int out_size, void* d_ws, size_t ws_size,
                              hipStream_t stream)
{
    const float* x    = (const float*)d_in[0];
    const float* e1w  = (const float*)d_in[1];
    const float* e1b  = (const float*)d_in[2];
    const float* e2w  = (const float*)d_in[3];
    const float* e2b  = (const float*)d_in[4];
    const float* e3w  = (const float*)d_in[5];
    const float* e3b  = (const float*)d_in[6];
    const float* emb  = (const float*)d_in[7];
    const float* d1w  = (const float*)d_in[8];
    const float* d1b  = (const float*)d_in[9];
    const float* d2w  = (const float*)d_in[10];
    const float* d2b  = (const float*)d_in[11];
    const float* d3w  = (const float*)d_in[12];
    const float* d3b  = (const float*)d_in[13];

    float* out = (float*)d_out;

    const int Bn = 16;
    const long long NZ1 = 16LL * 128 * HWSQ;   // 33554432
    const long long NZ2 = 16LL * 64  * HWSQ;   // 16777216
    const long long NZ3 = 16LL * 8   * HWSQ;   // 2097152
    const long long NOUT = 16LL * 156 * HWSQ;  // 40894464
    const int nrows = (int)(NZ3 / 8);          // 262144

    char* ws = (char*)d_ws;
    float* loss = (float*)ws;
    const size_t need_f32 = 16 + (size_t)(NZ1 + NZ2 + NZ3 + NZ3) * 4;

    zero_k<<<1, 1, 0, stream>>>(loss);

    if (ws_size >= need_f32) {
        float* b1 = (float*)(ws + 16);
        float* b2 = b1 + NZ1;
        float* b3 = b2 + NZ2;
        float* b4 = b3 + NZ3;

        conv3x3_k<float, float, float, 0, false><<<nblk(NZ1), 256, 0, stream>>>(x,  e1w, e1b, b1, Bn, 156, 128);
        conv3x3_k<float, float, float, 0, false><<<nblk(NZ2), 256, 0, stream>>>(b1, e2w, e2b, b2, Bn, 128, 64);
        conv3x3_k<float, float, float, 0, false><<<nblk(NZ3), 256, 0, stream>>>(b2, e3w, e3b, b3, Bn, 64, 8);
        vq_k<float><<<nblk(nrows), 256, 0, stream>>>(b3, emb, b4, loss, nrows);
        conv3x3_k<float, float, float, 0, true><<<nblk(NZ2), 256, 0, stream>>>(b4, d1w, d1b, b2, Bn, 8, 64);
        conv3x3_k<float, float, float, 0, true><<<nblk(NZ1), 256, 0, stream>>>(b2, d2w, d2b, b1, Bn, 64, 128);
        conv3x3_k<float, float, float, 1, true><<<nblk(NOUT), 256, 0, stream>>>(b1, d3w, d3b, out, Bn, 128, 156);
    } else {
        // bf16 intermediates fallback (110 MB)
        __hip_bfloat16* b1 = (__hip_bfloat16*)(ws + 16);
        __hip_bfloat16* b2 = b1 + NZ1;
        __hip_bfloat16* b3 = b2 + NZ2;
        __hip_bfloat16* b4 = b3 + NZ3;

        conv3x3_k<float, float, __hip_bfloat16, 0, false><<<nblk(NZ1), 256, 0, stream>>>(x,  e1w, e1b, b1, Bn, 156, 128);
        conv3x3_k<__hip_bfloat16, float, __hip_bfloat16, 0, false><<<nblk(NZ2), 256, 0, stream>>>(b1, e2w, e2b, b2, Bn, 128, 64);
        conv3x3_k<__hip_bfloat16, float, __hip_bfloat16, 0, false><<<nblk(NZ3), 256, 0, stream>>>(b2, e3w, e3b, b3, Bn, 64, 8);
        vq_k<__hip_bfloat16><<<nblk(nrows), 256, 0, stream>>>(b3, emb, b4, loss, nrows);
        conv3x3_k<__hip_bfloat16, float, __hip_bfloat16, 0, true><<<nblk(NZ2), 256, 0, stream>>>(b4, d1w, d1b, b2, Bn, 8, 64);
        conv3x3_k<__hip_bfloat16, float, __hip_bfloat16, 0, true><<<nblk(NZ1), 256, 0, stream>>>(b2, d2w, d2b, b1, Bn, 64, 128);
        conv3x3_k<__hip_bfloat16, float, float, 1, true><<<nblk(NOUT), 256, 0, stream>>>(b1, d3w, d3b, out, Bn, 128, 156);
    }

    fin_k<<<1, 1, 0, stream>>>(loss, out + NOUT);
}

// Round 3
// 1203.255 us; speedup vs baseline: 30.8813x; 30.8813x over previous
//
#include <hip/hip_runtime.h>
#include <hip/hip_bf16.h>

// VQ-VAE forward, MFMA implicit-GEMM version.
// Inputs/outputs fp32 (per reference). Intermediates NHWC bf16 in d_ws.
// Conv = 9-tap implicit GEMM: D[oc][pix] += W[oc][ic] * In[pix][ic] per (tap, ic-chunk).
// MFMA 16x16x32 bf16: A[m=lane&15][k=quad*8+j], B[k=quad*8+j][n=lane&15],
//                     D: col(n)=lane&15, row(m)=quad*4+reg   (learn_hip m89/m91/m120).

typedef __bf16 bf16x8 __attribute__((ext_vector_type(8)));
typedef float  floatx4 __attribute__((ext_vector_type(4)));

__device__ __forceinline__ unsigned short f2bf(float f) {
    return __builtin_bit_cast(unsigned short, __float2bfloat16(f));
}
__device__ __forceinline__ float bf2f(unsigned short u) {
    return __bfloat162float(__builtin_bit_cast(__hip_bfloat16, u));
}

// ---------------- x: NCHW fp32 -> NHWC bf16, C padded 156->160 -------------
__global__ __launch_bounds__(256) void xpose_k(const float* __restrict__ x,
                                               unsigned short* __restrict__ xn)
{
    __shared__ unsigned short t[64 * 168];   // 64 pixels x 160ch (stride 168)
    const int b = blockIdx.y;
    const int hw0 = blockIdx.x * 64;
    const int cl = threadIdx.x >> 6;         // 0..3
    const int hwl = threadIdx.x & 63;
    #pragma unroll 4
    for (int cc = 0; cc < 40; ++cc) {
        int c = cc * 4 + cl;
        float v = (c < 156) ? x[((size_t)(b * 156 + c) << 14) + hw0 + hwl] : 0.0f;
        t[hwl * 168 + c] = f2bf(v);
    }
    __syncthreads();
    for (int i = threadIdx.x; i < 64 * 20; i += 256) {
        int row = i / 20, qq = i - row * 20;
        uint4 v = *(const uint4*)(t + row * 168 + qq * 8);
        *(uint4*)(xn + ((size_t)((b << 14) + hw0 + row)) * 160 + qq * 8) = v;
    }
}

// ---------------- weight repack: fp32 -> Wrep[tap][oc][ic] bf16 ------------
__global__ __launch_bounds__(256) void repack_k(const float* __restrict__ w,
                                                unsigned short* __restrict__ wr,
                                                int Cout, int Cin, int OCP, int ICP,
                                                int trans, int n)
{
    int i = blockIdx.x * 256 + threadIdx.x;
    if (i >= n) return;
    int ic = i % ICP, rest = i / ICP;
    int oc = rest % OCP, tap = rest / OCP;
    float v = 0.0f;
    if (oc < Cout && ic < Cin) {
        // conv:  w[oc][ic][kh][kw] OIHW;  convT: w_eff[oc][ic][kh][kw]=w[ic][oc][2-kh][2-kw]
        v = trans ? w[(size_t)(ic * Cout + oc) * 9 + (8 - tap)]
                  : w[(size_t)(oc * Cin + ic) * 9 + tap];
    }
    wr[i] = f2bf(v);
}

// ---------------- zero helpers ----------------
__global__ void zero_k(float* p) { *p = 0.0f; }
__global__ __launch_bounds__(256) void zero4_k(uint4* __restrict__ p, int n4)
{
    int i = blockIdx.x * 256 + threadIdx.x;
    if (i < n4) p[i] = uint4{0, 0, 0, 0};
}

// ---------------- MFMA conv ----------------
// ICP: padded in-channels (buffer stride, mult of 32). OCB: oc per block (mult 16).
// OMODE 0: NHWC bf16 + relu (OUTC = out buffer C == real Cout)
// OMODE 1: NCHW bf16 + relu, predicate oc<OUTC
// OMODE 2: NCHW fp32 + sigmoid, predicate oc<OUTC
template <int ICP, int OCB, int OMODE, int OUTC>
__global__ __launch_bounds__(256) void conv_mfma(const unsigned short* __restrict__ in,
                                                 const unsigned short* __restrict__ wrep,
                                                 const float* __restrict__ bias,
                                                 void* __restrict__ outv, int OCP)
{
    constexpr int NOT = OCB / 16;
    constexpr int NICC = ICP / 32;
    __shared__ unsigned short tile[18 * 18 * 40];  // [pix 0..323][ic 0..31], pix stride 40

    const int tid  = threadIdx.x;
    const int lane = tid & 63, wave = tid >> 6;
    const int col  = lane & 15, quad = lane >> 4;
    const int ocblk = blockIdx.x, tix = blockIdx.y, b = blockIdx.z;
    const int h0 = (tix >> 3) << 4, w0 = (tix & 7) << 4;

    floatx4 acc[NOT][4];
    #pragma unroll
    for (int i = 0; i < NOT; ++i)
        #pragma unroll
        for (int r = 0; r < 4; ++r) acc[i][r] = floatx4{0.f, 0.f, 0.f, 0.f};

    for (int icc = 0; icc < NICC; ++icc) {
        __syncthreads();
        // stage (18x18 halo tile) x 32 ic, 16B per thread-item
        for (int s = tid; s < 18 * 18 * 4; s += 256) {
            int p = s >> 2, q = s & 3;
            int r = p / 18, c = p - r * 18;
            int gh = h0 - 1 + r, gw = w0 - 1 + c;
            uint4 v = uint4{0, 0, 0, 0};
            if ((unsigned)gh < 128u && (unsigned)gw < 128u) {
                size_t goff = ((size_t)(((b << 7) + gh) << 7) + gw) * ICP + icc * 32 + q * 8;
                v = *(const uint4*)(in + goff);
            }
            *(uint4*)(tile + p * 40 + q * 8) = v;
        }
        __syncthreads();

        #pragma unroll
        for (int tap = 0; tap < 9; ++tap) {
            const int dh = tap / 3, dw = tap % 3;
            bf16x8 bfr[4];
            #pragma unroll
            for (int rt = 0; rt < 4; ++rt) {
                int r = (wave << 2) + rt;
                int p = (r + dh) * 18 + col + dw;
                bfr[rt] = *(const bf16x8*)(tile + p * 40 + (quad << 3));
            }
            #pragma unroll
            for (int ot = 0; ot < NOT; ++ot) {
                int oc = ocblk * OCB + (ot << 4) + col;
                const unsigned short* wp =
                    wrep + ((size_t)(tap * OCP + oc)) * ICP + icc * 32 + (quad << 3);
                bf16x8 afr = *(const bf16x8*)wp;
                #pragma unroll
                for (int rt = 0; rt < 4; ++rt)
                    acc[ot][rt] = __builtin_amdgcn_mfma_f32_16x16x32_bf16(
                        afr, bfr[rt], acc[ot][rt], 0, 0, 0);
            }
        }
    }

    // epilogue. D: col=pixel w, row m = quad*4+reg = oc_local
    const int w = w0 + col;
    #pragma unroll
    for (int ot = 0; ot < NOT; ++ot) {
        int oc0 = ocblk * OCB + (ot << 4) + (quad << 2);
        #pragma unroll
        for (int rt = 0; rt < 4; ++rt) {
            int h = h0 + (wave << 2) + rt;
            if constexpr (OMODE == 0) {
                unsigned short* outp = (unsigned short*)outv;
                unsigned short pk[4];
                #pragma unroll
                for (int g = 0; g < 4; ++g) {
                    float v = acc[ot][rt][g] + bias[oc0 + g];
                    pk[g] = f2bf(fmaxf(v, 0.0f));
                }
                size_t off = ((size_t)(((b << 7) + h) << 7) + w) * OUTC + oc0;
                *(uint2*)(outp + off) = *(const uint2*)pk;   // 4 consecutive oc, 8B
            } else if constexpr (OMODE == 1) {
                unsigned short* outp = (unsigned short*)outv;
                #pragma unroll
                for (int g = 0; g < 4; ++g) {
                    int oc = oc0 + g;
                    if (oc < OUTC) {
                        float v = fmaxf(acc[ot][rt][g] + bias[oc], 0.0f);
                        outp[((size_t)(b * OUTC + oc) << 14) + (h << 7) + w] = f2bf(v);
                    }
                }
            } else {
                float* outp = (float*)outv;
                #pragma unroll
                for (int g = 0; g < 4; ++g) {
                    int oc = oc0 + g;
                    if (oc < OUTC) {
                        float v = acc[ot][rt][g] + bias[oc];
                        v = 1.0f / (1.0f + __expf(-v));
                        outp[((size_t)(b * OUTC + oc) << 14) + (h << 7) + w] = v;
                    }
                }
            }
        }
    }
}

// ---------------- vector quantizer ----------------
// z3: NCHW bf16 [16,8,128,128]; rows = 8 consecutive flat elements (= 8 w-pixels, one channel).
__global__ __launch_bounds__(256) void vq_k(const unsigned short* __restrict__ z,
                                            const float* __restrict__ emb,
                                            unsigned short* __restrict__ q,
                                            float* __restrict__ loss)
{
    __shared__ float se[512 * 8];
    __shared__ float se2[512];
    __shared__ float red[4];

    for (int i = threadIdx.x; i < 4096; i += 256) se[i] = emb[i];
    __syncthreads();
    for (int k = threadIdx.x; k < 512; k += 256) {
        float s = 0.0f;
        #pragma unroll
        for (int j = 0; j < 8; ++j) { float e = se[k * 8 + j]; s += e * e; }
        se2[k] = s;
    }
    __syncthreads();

    int r = blockIdx.x * 256 + threadIdx.x;   // grid sized exactly 262144
    uint4 raw = *(const uint4*)(z + (size_t)r * 8);
    const unsigned short* pr = (const unsigned short*)&raw;
    float zv[8];
    #pragma unroll
    for (int j = 0; j < 8; ++j) zv[j] = bf2f(pr[j]);

    float best = 3.4e38f;
    int bi = 0;
    for (int k = 0; k < 512; ++k) {
        float dot = 0.0f;
        #pragma unroll
        for (int j = 0; j < 8; ++j) dot += se[k * 8 + j] * zv[j];
        float d = se2[k] - 2.0f * dot;
        if (d < best) { best = d; bi = k; }   // strict <: first-min argmin
    }

    // r = ((b*8+c)*128 + h)*16 + wg
    int wg = r & 15, h = (r >> 4) & 127, c = (r >> 11) & 7, b = r >> 14;
    size_t pixbase = ((size_t)(((b << 7) + h) << 7)) + (wg << 3);
    float lsum = 0.0f;
    #pragma unroll
    for (int j = 0; j < 8; ++j) {
        float e = se[bi * 8 + j];
        q[(pixbase + j) * 32 + c] = f2bf(e);
        float df = e - zv[j];
        lsum += df * df;
    }

    for (int o = 32; o > 0; o >>= 1) lsum += __shfl_down(lsum, o, 64);
    int lane = threadIdx.x & 63, wv = threadIdx.x >> 6;
    if (lane == 0) red[wv] = lsum;
    __syncthreads();
    if (threadIdx.x == 0) atomicAdd(loss, red[0] + red[1] + red[2] + red[3]);
}

__global__ void fin_k(const float* __restrict__ loss, float* __restrict__ out)
{
    out[0] = 1.25f * (*loss) / 2097152.0f;
}

// ---------------- launch ----------------
extern "C" void kernel_launch(void* const* d_in, const int* in_sizes, int n_in,
                              void* d_out, int out_size, void* d_ws, size_t ws_size,
                              hipStream_t stream)
{
    const float* x   = (const float*)d_in[0];
    const float* e1w = (const float*)d_in[1];
    const float* e1b = (const float*)d_in[2];
    const float* e2w = (const float*)d_in[3];
    const float* e2b = (const float*)d_in[4];
    const float* e3w = (const float*)d_in[5];
    const float* e3b = (const float*)d_in[6];
    const float* emb = (const float*)d_in[7];
    const float* d1w = (const float*)d_in[8];
    const float* d1b = (const float*)d_in[9];
    const float* d2w = (const float*)d_in[10];
    const float* d2b = (const float*)d_in[11];
    const float* d3w = (const float*)d_in[12];
    const float* d3b = (const float*)d_in[13];
    float* out = (float*)d_out;

    char* ws = (char*)d_ws;
    size_t off = 0;
    auto alloc = [&](size_t bytes) { void* p = ws + off; off += (bytes + 255) & ~size_t(255); return p; };

    float*          loss  = (float*)alloc(4);
    unsigned short* wr_e1 = (unsigned short*)alloc((size_t)9 * 128 * 160 * 2);
    unsigned short* wr_e2 = (unsigned short*)alloc((size_t)9 * 64 * 128 * 2);
    unsigned short* wr_e3 = (unsigned short*)alloc((size_t)9 * 16 * 64 * 2);
    unsigned short* wr_d1 = (unsigned short*)alloc((size_t)9 * 64 * 32 * 2);
    unsigned short* wr_d2 = (unsigned short*)alloc((size_t)9 * 128 * 64 * 2);
    unsigned short* wr_d3 = (unsigned short*)alloc((size_t)9 * 192 * 128 * 2);
    unsigned short* z3    = (unsigned short*)alloc((size_t)16 * 8 * 16384 * 2);
    unsigned short* qb    = (unsigned short*)alloc((size_t)16 * 16384 * 32 * 2);
    unsigned short* S1    = (unsigned short*)alloc((size_t)16 * 16384 * 160 * 2); // xn -> b2 -> b4
    unsigned short* S2    = (unsigned short*)alloc((size_t)16 * 16384 * 128 * 2); // b1 -> b5
    (void)ws_size;

    zero_k<<<1, 1, 0, stream>>>(loss);
    // zero q (padded 32-ch NHWC; channels 8..31 must be 0)
    zero4_k<<<(16 * 16384 * 32 / 8 + 255) / 256, 256, 0, stream>>>((uint4*)qb, 16 * 16384 * 32 / 8);

    xpose_k<<<dim3(256, 16), 256, 0, stream>>>(x, S1);

    auto rp = [&](const float* w, unsigned short* wr, int Cout, int Cin, int OCP, int ICP, int trans) {
        int n = 9 * OCP * ICP;
        repack_k<<<(n + 255) / 256, 256, 0, stream>>>(w, wr, Cout, Cin, OCP, ICP, trans, n);
    };
    rp(e1w, wr_e1, 128, 156, 128, 160, 0);
    rp(e2w, wr_e2,  64, 128,  64, 128, 0);
    rp(e3w, wr_e3,   8,  64,  16,  64, 0);
    rp(d1w, wr_d1,  64,   8,  64,  32, 1);
    rp(d2w, wr_d2, 128,  64, 128,  64, 1);
    rp(d3w, wr_d3, 156, 128, 192, 128, 1);

    // encoder
    conv_mfma<160, 64, 0, 128><<<dim3(2, 64, 16), 256, 0, stream>>>(S1, wr_e1, e1b, S2, 128);
    conv_mfma<128, 64, 0,  64><<<dim3(1, 64, 16), 256, 0, stream>>>(S2, wr_e2, e2b, S1, 64);
    conv_mfma< 64, 16, 1,   8><<<dim3(1, 64, 16), 256, 0, stream>>>(S1, wr_e3, e3b, z3, 16);
    // VQ
    vq_k<<<1024, 256, 0, stream>>>(z3, emb, qb, loss);
    // decoder
    conv_mfma< 32, 64, 0,  64><<<dim3(1, 64, 16), 256, 0, stream>>>(qb, wr_d1, d1b, S1, 64);
    conv_mfma< 64, 64, 0, 128><<<dim3(2, 64, 16), 256, 0, stream>>>(S1, wr_d2, d2b, S2, 128);
    conv_mfma<128, 64, 2, 156><<<dim3(3, 64, 16), 256, 0, stream>>>(S2, wr_d3, d3b, out, 192);

    fin_k<<<1, 1, 0, stream>>>(loss, out + (size_t)16 * 156 * 16384);
}